// Round 22
// baseline (60.258 us; speedup 1.0000x reference)
//
#include <hip/hip_runtime.h>
#include <hip/hip_bf16.h>
#include <math.h>

constexpr int HW = 4096;   // 64*64

using bf8   = __attribute__((ext_vector_type(8))) short;   // 8 bf16 = 4 VGPR
using f32x4 = __attribute__((ext_vector_type(4))) float;

constexpr float SCALE = 0.17677669529663687f;  // 1/sqrt(32)

// load 8 consecutive f32 of a weight row, convert to a bf16 MFMA fragment
__device__ __forceinline__ bf8 ldW8(const float* p) {
    float4 a0 = *(const float4*)p;
    float4 a1 = *(const float4*)(p + 4);
    union { __hip_bfloat16 hh[8]; bf8 v; } pk;
    pk.hh[0] = __float2bfloat16(a0.x); pk.hh[1] = __float2bfloat16(a0.y);
    pk.hh[2] = __float2bfloat16(a0.z); pk.hh[3] = __float2bfloat16(a0.w);
    pk.hh[4] = __float2bfloat16(a1.x); pk.hh[5] = __float2bfloat16(a1.y);
    pk.hh[6] = __float2bfloat16(a1.z); pk.hh[7] = __float2bfloat16(a1.w);
    return pk.v;
}

// ---------------------------------------------------------------------------
// fused_one: the ENTIRE op in one dispatch, no cross-block dependencies.
// Block = (b, 2x8 px tile), 512 thr = 8 waves. Each block recomputes its own
// Q (16px x 256), K/V halo (8x16 px x 256) via MFMA from x + raw f32 weights
// (cvt in-register -> bit-identical to the split version), then runs the
// validated attn+proj phases from LDS. Halo OOB px forced to K=V=0 (unfold
// zero-pad semantics). LDS 144.25 KB (dynamic), 1 block/CU, grid = 2 rounds.
// Phases: stage-x | Q,K GEMM | QK+exp+P | V GEMM (over K region) | PV->AB | proj
// ---------------------------------------------------------------------------
__global__ __launch_bounds__(512) void fused_one(
    const float* __restrict__ x,
    const float* __restrict__ Wk, const float* __restrict__ Wq,
    const float* __restrict__ Wv, const float* __restrict__ Wo,
    const float* __restrict__ bk, const float* __restrict__ bq,
    const float* __restrict__ bv, const float* __restrict__ bo,
    float* __restrict__ out)
{
    extern __shared__ __align__(16) unsigned short LDS[];
    unsigned short* XT = LDS;            // x halo  [128 px][136]   (34.0 KB)
    unsigned short* KT = LDS + 17408;    // K [128][264] / V [256][136] (68 KB)
    unsigned short* QT = LDS + 52224;    // Q [16][264]; later AB    (8.25 KB)
    unsigned short* P  = LDS + 56448;    // per-wave P strips        (34.0 KB)

    int bid  = blockIdx.x;
    int b    = bid >> 8;
    int tile = bid & 255;
    int ty0  = (tile >> 3) * 2;
    int tx0  = (tile & 7) * 8;

    int t  = threadIdx.x;
    int w  = t >> 6;      // wave id; = head in attn phase
    int l  = t & 63;
    int lr = l & 15;
    int g  = l >> 4;
    int h  = w;

    // ================= phase 1: stage x halo (clamped; OOB zeroed later) ====
    {
        int hcol = t & 15;
        int hrow = (t >> 4) & 7;
        int cq   = t >> 7;            // 0..3 channel quarter
        int ir = ty0 + hrow - 3; ir = ir < 0 ? 0 : (ir > 63 ? 63 : ir);
        int ic = tx0 + hcol - 4; ic = ic < 0 ? 0 : (ic > 63 ? 63 : ic);
        const float* xp = x + ((size_t)b * 128 + cq * 32) * HW + ir * 64 + ic;
        int hb = (hrow * 16 + hcol) * 136 + cq * 32;
        #pragma unroll
        for (int i = 0; i < 32; i += 2) {
            __hip_bfloat16 h0 = __float2bfloat16(xp[(size_t)i * HW]);
            __hip_bfloat16 h1 = __float2bfloat16(xp[(size_t)(i + 1) * HW]);
            unsigned u = (unsigned)*(unsigned short*)&h0 |
                         ((unsigned)*(unsigned short*)&h1 << 16);
            *(unsigned*)&XT[hb + i] = u;
        }
    }
    __syncthreads();

    // ================= phase 2: Q-GEMM + K-GEMM ============================
    {
        // ---- Q: wave w computes oc-tiles 2w, 2w+1 for the 16 center px ----
        int hpQ = ((lr >> 3) + 3) * 16 + (lr & 7) + 4;   // center px -> halo idx
        #pragma unroll
        for (int oi = 0; oi < 2; ++oi) {
            int ot = w * 2 + oi;
            f32x4 acc = {0.f, 0.f, 0.f, 0.f};
            #pragma unroll
            for (int ks = 0; ks < 4; ++ks) {
                bf8 aX = *(const bf8*)&XT[hpQ * 136 + ks * 32 + g * 8];
                bf8 bW = ldW8(Wq + (size_t)(ot * 16 + lr) * 128 + ks * 32 + g * 8);
                acc = __builtin_amdgcn_mfma_f32_16x16x32_bf16(aX, bW, acc, 0, 0, 0);
            }
            float bval = bq[ot * 16 + lr];
            #pragma unroll
            for (int r = 0; r < 4; ++r) {
                float v = (acc[r] + bval) * SCALE;
                __hip_bfloat16 hv = __float2bfloat16(v);
                unsigned us = *(unsigned short*)&hv;
                unsigned un = __shfl_xor((int)us, 1);
                if (!(l & 1))
                    *(unsigned*)&QT[(g * 4 + r) * 264 + ot * 16 + lr] = us | (un << 16);
            }
        }
        // ---- K: wave w computes oc-tiles 2w,2w+1 for all 128 halo px ----
        bf8 bW[2][4];
        float bvalK[2];
        #pragma unroll
        for (int oi = 0; oi < 2; ++oi) {
            int ot = w * 2 + oi;
            #pragma unroll
            for (int ks = 0; ks < 4; ++ks)
                bW[oi][ks] = ldW8(Wk + (size_t)(ot * 16 + lr) * 128 + ks * 32 + g * 8);
            bvalK[oi] = bk[ot * 16 + lr];
        }
        #pragma unroll
        for (int pt = 0; pt < 8; ++pt) {
            bf8 aX[4];
            #pragma unroll
            for (int ks = 0; ks < 4; ++ks)
                aX[ks] = *(const bf8*)&XT[(pt * 16 + lr) * 136 + ks * 32 + g * 8];
            int ir = ty0 + pt - 3;
            bool rok = (ir >= 0) && (ir < 64);
            #pragma unroll
            for (int oi = 0; oi < 2; ++oi) {
                f32x4 acc = {0.f, 0.f, 0.f, 0.f};
                #pragma unroll
                for (int ks = 0; ks < 4; ++ks)
                    acc = __builtin_amdgcn_mfma_f32_16x16x32_bf16(aX[ks], bW[oi][ks], acc, 0, 0, 0);
                int ot = w * 2 + oi;
                #pragma unroll
                for (int r = 0; r < 4; ++r) {
                    int ic = tx0 + g * 4 + r - 4;
                    bool ok = rok && (ic >= 0) && (ic < 64);
                    float v = ok ? (acc[r] + bvalK[oi]) : 0.f;
                    __hip_bfloat16 hv = __float2bfloat16(v);
                    unsigned us = *(unsigned short*)&hv;
                    unsigned un = __shfl_xor((int)us, 1);
                    if (!(l & 1))
                        *(unsigned*)&KT[(pt * 16 + g * 4 + r) * 264 + ot * 16 + lr] =
                            us | (un << 16);
                }
            }
        }
    }
    __syncthreads();

    // ================= phase 3: QK + masked exp + P (wave = head) ==========
    unsigned short* pw = &P[w * 2176];
    float rsum[4];
    {
        bf8 aQ = *(const bf8*)&QT[lr * 264 + h * 32 + g * 8];
        f32x4 acc8[8];
        #pragma unroll
        for (int i = 0; i < 8; ++i) {
            bf8 bK = *(const bf8*)&KT[(i * 16 + lr) * 264 + h * 32 + g * 8];
            f32x4 z = {0.f, 0.f, 0.f, 0.f};
            acc8[i] = __builtin_amdgcn_mfma_f32_16x16x32_bf16(aQ, bK, z, 0, 0, 0);
        }
        int gy2 = g >> 1;
        rsum[0] = rsum[1] = rsum[2] = rsum[3] = 0.f;
        #pragma unroll
        for (int i = 0; i < 8; ++i) {
            bool dyok = ((unsigned)(i - gy2)) <= 6u;
            #pragma unroll
            for (int reg = 0; reg < 4; ++reg) {
                int px_ = ((g & 1) << 2) + reg;
                bool ok = dyok && (((unsigned)(lr - px_ - 1)) <= 6u);
                float e = ok ? __expf(acc8[i][reg]) : 0.f;
                rsum[reg] += e;
                __hip_bfloat16 hb = __float2bfloat16(e);
                unsigned us = *(unsigned short*)&hb;
                unsigned un = __shfl_xor((int)us, 1);
                if (!(l & 1))
                    *(unsigned*)&pw[(g * 4 + reg) * 136 + i * 16 + lr] = us | (un << 16);
            }
        }
        #pragma unroll
        for (int reg = 0; reg < 4; ++reg) {
            float sm = rsum[reg];
            sm += __shfl_xor(sm, 1);
            sm += __shfl_xor(sm, 2);
            sm += __shfl_xor(sm, 4);
            sm += __shfl_xor(sm, 8);
            rsum[reg] = 1.f / sm;
        }
    }
    __syncthreads();   // all QK reads of KT done -> V may overwrite

    // ================= phase 4: V-GEMM -> VT ch-major (over KT region) =====
    unsigned short* VT = KT;   // [256 ch][136 px-stride]
    {
        bf8 bW[2][4];
        float bvalV[2];
        #pragma unroll
        for (int oi = 0; oi < 2; ++oi) {
            int ot = w * 2 + oi;
            #pragma unroll
            for (int ks = 0; ks < 4; ++ks)
                bW[oi][ks] = ldW8(Wv + (size_t)(ot * 16 + lr) * 128 + ks * 32 + g * 8);
            bvalV[oi] = bv[ot * 16 + lr];
        }
        #pragma unroll
        for (int pt = 0; pt < 8; ++pt) {
            bf8 aX[4];
            #pragma unroll
            for (int ks = 0; ks < 4; ++ks)
                aX[ks] = *(const bf8*)&XT[(pt * 16 + lr) * 136 + ks * 32 + g * 8];
            int ir = ty0 + pt - 3;
            bool rok = (ir >= 0) && (ir < 64);
            #pragma unroll
            for (int oi = 0; oi < 2; ++oi) {
                f32x4 acc = {0.f, 0.f, 0.f, 0.f};
                #pragma unroll
                for (int ks = 0; ks < 4; ++ks)
                    acc = __builtin_amdgcn_mfma_f32_16x16x32_bf16(aX[ks], bW[oi][ks], acc, 0, 0, 0);
                int ot = w * 2 + oi;
                union { __hip_bfloat16 h4[4]; uint2 u; } pk;
                #pragma unroll
                for (int r = 0; r < 4; ++r) {
                    int ic = tx0 + g * 4 + r - 4;
                    bool ok = rok && (ic >= 0) && (ic < 64);
                    pk.h4[r] = __float2bfloat16(ok ? (acc[r] + bvalV[oi]) : 0.f);
                }
                *(uint2*)&VT[(size_t)(ot * 16 + lr) * 136 + pt * 16 + g * 4] = pk.u;
            }
        }
    }
    __syncthreads();   // VT ready

    // ================= phase 5: PV -> AB (over QT region) ==================
    unsigned short* AB = QT;
    {
        f32x4 pv[2] = { {0.f,0.f,0.f,0.f}, {0.f,0.f,0.f,0.f} };
        #pragma unroll
        for (int ks = 0; ks < 4; ++ks) {
            bf8 aP = *(const bf8*)&pw[lr * 136 + ks * 32 + g * 8];
            int yq = 2 * ks + (g >> 1);
            int xv = (g & 1) << 3;
            #pragma unroll
            for (int nt2 = 0; nt2 < 2; ++nt2) {
                bf8 bV = *(const bf8*)&VT[(size_t)(h * 32 + nt2 * 16 + lr) * 136 +
                                          yq * 16 + xv];
                pv[nt2] = __builtin_amdgcn_mfma_f32_16x16x32_bf16(aP, bV, pv[nt2], 0, 0, 0);
            }
        }
        #pragma unroll
        for (int nt2 = 0; nt2 < 2; ++nt2) {
            #pragma unroll
            for (int reg = 0; reg < 4; ++reg) {
                float ov = pv[nt2][reg] * rsum[reg];
                __hip_bfloat16 hb = __float2bfloat16(ov);
                unsigned us = *(unsigned short*)&hb;
                unsigned un = __shfl_xor((int)us, 1);
                if (!(l & 1)) {
                    int rloc = g * 4 + reg;
                    *(unsigned*)&AB[rloc * 264 + h * 32 + nt2 * 16 + lr] = us | (un << 16);
                }
            }
        }
    }
    __syncthreads();

    // ================= phase 6: output projection ==========================
    {
        f32x4 po = {0.f, 0.f, 0.f, 0.f};
        #pragma unroll
        for (int ks = 0; ks < 8; ++ks) {
            bf8 aA  = *(const bf8*)&AB[lr * 264 + ks * 32 + g * 8];
            bf8 bWo = ldW8(Wo + (size_t)(w * 16 + lr) * 256 + ks * 32 + g * 8);
            po = __builtin_amdgcn_mfma_f32_16x16x32_bf16(aA, bWo, po, 0, 0, 0);
        }
        int oc = w * 16 + lr;
        float bval = bo[oc];
        int q_  = g * 4;
        int py  = q_ >> 3;
        int px_ = q_ & 7;
        float4 r4 = make_float4(po[0] + bval, po[1] + bval,
                                po[2] + bval, po[3] + bval);
        *(float4*)&out[((size_t)b * 128 + oc) * 4096 + (ty0 + py) * 64 + tx0 + px_] = r4;
    }
}

// ---------------------------------------------------------------------------
extern "C" void kernel_launch(void* const* d_in, const int* in_sizes, int n_in,
                              void* d_out, int out_size, void* d_ws, size_t ws_size,
                              hipStream_t stream) {
    const float* x  = (const float*)d_in[0];
    const float* Wk = (const float*)d_in[1];
    const float* bk = (const float*)d_in[2];
    const float* Wq = (const float*)d_in[3];
    const float* bq = (const float*)d_in[4];
    const float* Wv = (const float*)d_in[5];
    const float* bv = (const float*)d_in[6];
    const float* Wo = (const float*)d_in[7];
    const float* bo = (const float*)d_in[8];
    float* out = (float*)d_out;

    constexpr int LDS_BYTES = 147712;   // 73856 shorts
    hipFuncSetAttribute((const void*)fused_one,
                        hipFuncAttributeMaxDynamicSharedMemorySize, LDS_BYTES);
    fused_one<<<dim3(512), dim3(512), LDS_BYTES, stream>>>(
        x, Wk, Wq, Wv, Wo, bk, bq, bv, bo, out);
}

// Round 23
// 41.504 us; speedup vs baseline: 1.4518x; 1.4518x over previous
//
#include <hip/hip_runtime.h>
#include <hip/hip_bf16.h>
#include <math.h>

constexpr int HW = 4096;   // 64*64

using bf8   = __attribute__((ext_vector_type(8))) short;   // 8 bf16 = 4 VGPR
using f32x4 = __attribute__((ext_vector_type(4))) float;

constexpr float SCALE = 0.17677669529663687f;  // 1/sqrt(32)

// Kc: [b][70][70] padded pixels x 256 bf16 ch (pixel-major K; row/col pad +3)
// Vc: [b][256 ch][70 rows][80 stride] bf16 (channel-major V; row pad +3, col pad +4)
// Qb: [8192 px][256 ch] bf16, pre-scaled by 1/sqrt(32)

// ---------------------------------------------------------------------------
// qkv_fused: grid (140, 4).
//  bx < 128: block = (px-tile bx, oc-quarter y). Stage x-tile ONCE into
//            frag-ordered LDS, then loop s in {K,Q,V}: stage weight slice,
//            16 MFMAs, scatter to Kc/Qb/Vc.
//  bx >= 128: 48 aux works (Kc/Vc borders + Wob bf16).
// ---------------------------------------------------------------------------
__global__ __launch_bounds__(256) void qkv_fused(
    const float* __restrict__ x,
    const float* __restrict__ Wk, const float* __restrict__ Wq,
    const float* __restrict__ Wv, const float* __restrict__ Wo,
    const float* __restrict__ bk, const float* __restrict__ bq,
    const float* __restrict__ bv,
    unsigned short* __restrict__ Qb, unsigned short* __restrict__ Kc,
    unsigned short* __restrict__ Vc, __hip_bfloat16* __restrict__ Wob)
{
    int bx = blockIdx.x, y = blockIdx.y;
    int t  = threadIdx.x;

    if (bx >= 128) {
        // ---- aux: borders + Wob (48 works) ----
        int a    = (bx - 128) * 4 + y;        // 0..47
        int base = a * 256 + t;
        const int STR = 48 * 256;
        for (int i = base; i < 120832; i += STR) {
            int plane = i / 236;
            int c8    = i - plane * 236;
            int byteoff;
            if (c8 < 108) {
                int r6  = c8 / 18;
                int o8  = c8 - r6 * 18;
                int row = r6 < 3 ? r6 : 64 + r6;
                byteoff = row * 160 + o8 * 8;
            } else {
                int s   = c8 - 108;
                int row = 3 + (s >> 1);
                byteoff = row * 160 + ((s & 1) ? 136 : 0);
            }
            *(uint2*)((char*)Vc + (size_t)plane * 11200 + byteoff) = make_uint2(0u, 0u);
        }
        for (int i = base; i < 51456; i += STR) {
            int b   = i >= 25728;
            int r   = i - 25728 * b;
            int pxi = r >> 5;
            int sub = r & 31;
            int yy, xx;
            if (pxi < 420) {
                int r70 = pxi / 70;
                yy = r70 < 3 ? r70 : 64 + r70;
                xx = pxi - r70 * 70;
            } else {
                int q = pxi - 420;
                yy = q / 6 + 3;
                int c6 = q - (yy - 3) * 6;
                xx = c6 < 3 ? c6 : 64 + c6;
            }
            *(uint4*)&Kc[((size_t)b * 4900 + yy * 70 + xx) * 256 + sub * 8] =
                make_uint4(0u, 0u, 0u, 0u);
        }
        for (int i = base; i < 32768; i += STR)
            Wob[i] = __float2bfloat16(Wo[i]);
        return;
    }

    // ---- main GEMM block: one x-tile, three weight slices ----
    __shared__ __align__(16) unsigned short Xl[8192];  // 16 frags x 512 shorts
    __shared__ __align__(16) unsigned short Wl[8192];

    int b   = bx >> 6;
    int px0 = bx * 64;
    int hw0 = px0 & 4095;
    int ocl = y * 64;

    // stage x tile (64 px x 128 ch) -> frag-ordered Xl (ONCE)
    {
        int px = t >> 2;
        int q  = t & 3;
        int wv = px >> 4, mm = px & 15;
        const float* xp = x + ((size_t)b * 128 + q * 32) * HW + hw0 + px;
        int dbase = (wv * 4 + q) * 512 + mm * 8;
        #pragma unroll
        for (int kq = 0; kq < 4; ++kq) {
            union { __hip_bfloat16 hh[8]; uint4 u; } pk;
            #pragma unroll
            for (int j = 0; j < 8; ++j)
                pk.hh[j] = __float2bfloat16(xp[(size_t)(kq * 8 + j) * HW]);
            *(uint4*)&Xl[dbase + kq * 128] = pk.u;
        }
    }
    __syncthreads();

    int w = t >> 6, lane = t & 63;
    int m  = lane & 15;
    int kq = lane >> 4;
    int pxw = px0 + w * 16;

    bf8 aF[4];
    #pragma unroll
    for (int ks = 0; ks < 4; ++ks)
        aF[ks] = *(const bf8*)&Xl[(w * 4 + ks) * 512 + lane * 8];

    const float* Wms[3]    = { Wk, Wq, Wv };
    const float* biases[3] = { bk, bq, bv };

    #pragma unroll 1
    for (int s = 0; s < 3; ++s) {
        // stage weight slice (64 oc x 128 ch) -> frag-ordered Wl
        {
            int oc = t >> 2;
            int q  = t & 3;
            int of = oc >> 4, mo = oc & 15;
            const float* wp = Wms[s] + (size_t)(ocl + oc) * 128 + q * 32;
            int dbw = (of * 4 + q) * 512 + mo * 8;
            #pragma unroll
            for (int kq2 = 0; kq2 < 4; ++kq2) {
                float4 a0 = *(const float4*)(wp + kq2 * 8);
                float4 a1 = *(const float4*)(wp + kq2 * 8 + 4);
                union { __hip_bfloat16 hh[8]; uint4 u; } pk;
                pk.hh[0] = __float2bfloat16(a0.x); pk.hh[1] = __float2bfloat16(a0.y);
                pk.hh[2] = __float2bfloat16(a0.z); pk.hh[3] = __float2bfloat16(a0.w);
                pk.hh[4] = __float2bfloat16(a1.x); pk.hh[5] = __float2bfloat16(a1.y);
                pk.hh[6] = __float2bfloat16(a1.z); pk.hh[7] = __float2bfloat16(a1.w);
                *(uint4*)&Wl[dbw + kq2 * 128] = pk.u;
            }
        }
        __syncthreads();

        f32x4 acc[4] = { {0.f,0.f,0.f,0.f}, {0.f,0.f,0.f,0.f},
                         {0.f,0.f,0.f,0.f}, {0.f,0.f,0.f,0.f} };
        #pragma unroll
        for (int ks = 0; ks < 4; ++ks) {
            #pragma unroll
            for (int of = 0; of < 4; ++of) {
                bf8 bF = *(const bf8*)&Wl[(of * 4 + ks) * 512 + lane * 8];
                acc[of] = __builtin_amdgcn_mfma_f32_16x16x32_bf16(aF[ks], bF, acc[of], 0, 0, 0);
            }
        }

        const float* bias = biases[s];
        if (s == 1) {
            // Q: pre-scale, bf16, pair over ch, even-m 4B stores
            #pragma unroll
            for (int of = 0; of < 4; ++of) {
                float bval = bias[ocl + of * 16 + m];
                #pragma unroll
                for (int r = 0; r < 4; ++r) {
                    int px = pxw + kq * 4 + r;
                    float v = (acc[of][r] + bval) * SCALE;
                    __hip_bfloat16 hv = __float2bfloat16(v);
                    unsigned us = *(unsigned short*)&hv;
                    unsigned un = __shfl_xor((int)us, 1);
                    if (!(m & 1))
                        *(unsigned*)&Qb[(size_t)px * 256 + ocl + of * 16 + m] = us | (un << 16);
                }
            }
        } else if (s == 0) {
            // K: padded pixel-major, pair over ch
            #pragma unroll
            for (int of = 0; of < 4; ++of) {
                float bval = bias[ocl + of * 16 + m];
                #pragma unroll
                for (int r = 0; r < 4; ++r) {
                    int px = pxw + kq * 4 + r;
                    int bb = px >> 12, hw = px & 4095;
                    int yy = hw >> 6, xx = hw & 63;
                    __hip_bfloat16 hv = __float2bfloat16(acc[of][r] + bval);
                    unsigned us = *(unsigned short*)&hv;
                    unsigned un = __shfl_xor((int)us, 1);
                    if (!(m & 1))
                        *(unsigned*)&Kc[((size_t)bb * 4900 + (yy + 3) * 70 + xx + 3) * 256
                                        + ocl + of * 16 + m] = us | (un << 16);
                }
            }
        } else {
            // V: channel-major planes [256][70][80]; 4 consecutive px -> 8B store
            #pragma unroll
            for (int of = 0; of < 4; ++of) {
                float bval = bias[ocl + of * 16 + m];
                int ch = ocl + of * 16 + m;
                union { __hip_bfloat16 h[4]; uint2 u; } pk;
                #pragma unroll
                for (int r = 0; r < 4; ++r)
                    pk.h[r] = __float2bfloat16(acc[of][r] + bval);
                int px = pxw + kq * 4;
                int bb = px >> 12, hw = px & 4095;
                int yy = hw >> 6, xx = hw & 63;
                *(uint2*)&Vc[((size_t)bb * 256 + ch) * 5600 + (yy + 3) * 80 + xx + 4] = pk.u;
            }
        }
        __syncthreads();   // before Wl overwrite next iter
    }
}

// ---------------------------------------------------------------------------
// attn_proj: fused attention + output projection, 2x8 tile (1 strip/wave).
// Block = (b, 2x8 pixel tile): grid 512, 512 threads = 8 waves, wave = head.
// Wave: QK 8 MFMA -> mask/exp/pack -> PV 8 MFMA -> AB (LDS, 16px x 256ch).
// __syncthreads. Proj: wave = 16-oc slice: 8 MFMAs from AB x Wob -> out.
// launch_bounds(512,4): VGPR<=128 -> 2 blocks/CU -> 4 waves/SIMD.
// ---------------------------------------------------------------------------
__global__ __launch_bounds__(512, 4) void attn_proj(
    const unsigned short* __restrict__ Qb, const unsigned short* __restrict__ Kc,
    const unsigned short* __restrict__ Vc, const __hip_bfloat16* __restrict__ Wob,
    const float* __restrict__ bo, float* __restrict__ out)
{
    __shared__ __align__(16) unsigned short P[8 * 2176];   // per-wave P strips
    __shared__ __align__(16) unsigned short AB[16 * 264];  // attn tile 16px x 256ch

    int id   = blockIdx.x;
    int b    = id >> 8;
    int tile = id & 255;
    int ty0  = (tile >> 3) * 2;
    int tx0  = (tile & 7) * 8;

    int t  = threadIdx.x;
    int w  = t >> 6;      // wave = head
    int l  = t & 63;
    int lr = l & 15;
    int g  = l >> 4;
    int h  = w;

    unsigned short* pw = &P[w * 2176];
    const unsigned short* kcb = Kc + (size_t)b * (4900 * 256) + h * 32 + g * 8;

    int apy = lr >> 3;
    int apx = lr & 7;
    bf8 aQ = *(const bf8*)(Qb +
        ((size_t)b * 4096 + (ty0 + apy) * 64 + tx0 + apx) * 256 + h * 32 + g * 8);

    f32x4 acc[8];
    #pragma unroll
    for (int i = 0; i < 8; ++i) {
        bf8 bK = *(const bf8*)(kcb + ((size_t)(ty0 + i) * 70 + tx0 + lr - 1) * 256);
        f32x4 z = {0.f, 0.f, 0.f, 0.f};
        acc[i] = __builtin_amdgcn_mfma_f32_16x16x32_bf16(aQ, bK, z, 0, 0, 0);
    }

    int gy2 = g >> 1;
    float rsum[4] = {0.f, 0.f, 0.f, 0.f};
    #pragma unroll
    for (int i = 0; i < 8; ++i) {
        bool dyok = ((unsigned)(i - gy2)) <= 6u;
        #pragma unroll
        for (int reg = 0; reg < 4; ++reg) {
            int px_ = ((g & 1) << 2) + reg;
            bool ok = dyok && (((unsigned)(lr - px_ - 1)) <= 6u);
            float e = ok ? __expf(acc[i][reg]) : 0.f;
            rsum[reg] += e;
            __hip_bfloat16 hb = __float2bfloat16(e);
            unsigned us = *(unsigned short*)&hb;
            unsigned un = __shfl_xor((int)us, 1);
            if (!(l & 1))
                *(unsigned*)&pw[(g * 4 + reg) * 136 + i * 16 + lr] = us | (un << 16);
        }
    }
    #pragma unroll
    for (int reg = 0; reg < 4; ++reg) {
        float sm = rsum[reg];
        sm += __shfl_xor(sm, 1);
        sm += __shfl_xor(sm, 2);
        sm += __shfl_xor(sm, 4);
        sm += __shfl_xor(sm, 8);
        rsum[reg] = 1.f / sm;
    }

    f32x4 pv[2] = { {0.f,0.f,0.f,0.f}, {0.f,0.f,0.f,0.f} };
    #pragma unroll
    for (int ks = 0; ks < 4; ++ks) {
        bf8 aP = *(const bf8*)&pw[lr * 136 + ks * 32 + g * 8];
        int yq = 2 * ks + (g >> 1);
        int xv = (g & 1) << 3;
        #pragma unroll
        for (int nt2 = 0; nt2 < 2; ++nt2) {
            bf8 bV = *(const bf8*)(Vc +
                ((size_t)b * 256 + h * 32 + nt2 * 16 + lr) * 5600 +
                (ty0 + yq) * 80 + tx0 + xv);
            pv[nt2] = __builtin_amdgcn_mfma_f32_16x16x32_bf16(aP, bV, pv[nt2], 0, 0, 0);
        }
    }

    #pragma unroll
    for (int nt2 = 0; nt2 < 2; ++nt2) {
        #pragma unroll
        for (int reg = 0; reg < 4; ++reg) {
            float ov = pv[nt2][reg] * rsum[reg];
            __hip_bfloat16 hb = __float2bfloat16(ov);
            unsigned us = *(unsigned short*)&hb;
            unsigned un = __shfl_xor((int)us, 1);
            if (!(l & 1)) {
                int rloc = g * 4 + reg;
                *(unsigned*)&AB[rloc * 264 + h * 32 + nt2 * 16 + lr] = us | (un << 16);
            }
        }
    }
    __syncthreads();

    f32x4 po = {0.f, 0.f, 0.f, 0.f};
    #pragma unroll
    for (int ks = 0; ks < 8; ++ks) {
        bf8 aA = *(const bf8*)&AB[lr * 264 + ks * 32 + g * 8];
        bf8 bF = *(const bf8*)((const unsigned short*)Wob +
                 (size_t)(w * 16 + lr) * 256 + ks * 32 + g * 8);
        po = __builtin_amdgcn_mfma_f32_16x16x32_bf16(aA, bF, po, 0, 0, 0);
    }
    {
        int oc = w * 16 + lr;
        float bval = bo[oc];
        int q_  = g * 4;
        int py  = q_ >> 3;
        int px_ = q_ & 7;
        float4 r4 = make_float4(po[0] + bval, po[1] + bval,
                                po[2] + bval, po[3] + bval);
        *(float4*)&out[((size_t)b * 128 + oc) * 4096 + (ty0 + py) * 64 + tx0 + px_] = r4;
    }
}

// ---------------------------------------------------------------------------
extern "C" void kernel_launch(void* const* d_in, const int* in_sizes, int n_in,
                              void* d_out, int out_size, void* d_ws, size_t ws_size,
                              hipStream_t stream) {
    const float* x  = (const float*)d_in[0];
    const float* Wk = (const float*)d_in[1];
    const float* bk = (const float*)d_in[2];
    const float* Wq = (const float*)d_in[3];
    const float* bq = (const float*)d_in[4];
    const float* Wv = (const float*)d_in[5];
    const float* bv = (const float*)d_in[6];
    const float* Wo = (const float*)d_in[7];
    const float* bo = (const float*)d_in[8];
    float* out = (float*)d_out;

    char* wsb = (char*)d_ws;
    unsigned short* Qb  = (unsigned short*)wsb;                          // 4 MB
    unsigned short* Kc  = (unsigned short*)(wsb + (4u << 20));           // ~4.8 MB
    unsigned short* Vc  = (unsigned short*)(wsb + (9u << 20));           // ~5.5 MB
    __hip_bfloat16* Wob = (__hip_bfloat16*)(wsb + (15u << 20));          // 64 KB

    qkv_fused<<<dim3(140, 4), 256, 0, stream>>>(
        x, Wk, Wq, Wv, Wo, bk, bq, bv, Qb, Kc, Vc, Wob);
    attn_proj<<<dim3(512), 512, 0, stream>>>(Qb, Kc, Vc, Wob, bo, out);
}